// Round 7
// baseline (3945.385 us; speedup 1.0000x reference)
//
#include <hip/hip_runtime.h>
#include <stdint.h>

// ---------------------------------------------------------------------------
// RNN scan, fp32. Phase 1: u = tanh(x@Wi^T+bi) into states region.
// Phase 2: persistent scan, 8 groups (8 batches) x 16 h-slices (32 h).
//   ROUND 7 = round-3 (PASSED, 2332 us) + ONE change: split fast/slow
//   exchange buffers. Fast buffer sees ONLY sc0 stores + sc0 polls -> its
//   lines stay resident in the producer XCD's L2 (round-3's same-address
//   sc0 sc1 store write-through invalidated the L2 copy, pushing every
//   "fast" poll out to L3 -- the x4 gap between modeled ~1300 cy/step and
//   observed ~5470 cy/step). Slow mirror at +SLOW_OFF gets the sc0 sc1
//   write-through duplicate; dev-fallback polls (every 4th try) read it,
//   so correctness never depends on WG->XCD placement. ws = 512 KB.
//   Everything else identical to round 3:
//   * g = wg&7 -> group's 16 WGs co-locate on one XCD (perf heuristic).
//   * SAMPLE-THEN-BULK polling: spin on a 1-dword/lane probe (all 16
//     slices witnessed per wave), then ONE verified bulk 16KB read.
//     Tagged words (tag t+1 | f16) carry ALL correctness; 0xAA poison =
//     tag 0xAAAA never matches.
//   * Wave role split: waves 0,1 compute+publish (Wh slice in 64 VGPRs,
//     two independent 8-MFMA chains, setprio(1)); waves 2,3 poll+write AF.
//   * ONE raw s_barrier per step, lgkmcnt(0) only -- no vmcnt(0) drain.
//   * u prefetched one step ahead into registers; retired by a counted
//     s_waitcnt vmcnt(16) (12 publish stores + 4 next-u loads younger).
//   * AF swizzle byte(m,c) = m*1024 + (c ^ ((m&7)<<4)): conflict-free
//     ds_write_b64 unpack and ds_read_b128 fragment reads.
// ---------------------------------------------------------------------------

typedef _Float16 half8 __attribute__((ext_vector_type(8)));
typedef float    f32x4 __attribute__((ext_vector_type(4)));
typedef uint32_t u32x4 __attribute__((ext_vector_type(4)));

#define T_STEPS 1024
#define NHID    512
#define NIN     128
#define NBATCH  64
#define STATES_ELEMS (NBATCH * T_STEPS * NHID)  // 33554432
#define SLOW_OFF 65536                          // dwords: fast -> slow mirror

__device__ __forceinline__ float tanh_fast(float x) {
  float e = __expf(2.0f * x);
  return 1.0f - 2.0f * __builtin_amdgcn_rcpf(e + 1.0f);
}
__device__ __forceinline__ uint32_t f16b(float s) {
  return (uint32_t)__builtin_bit_cast(unsigned short, (_Float16)s);
}
__device__ __forceinline__ uint32_t fbits(float s) {
  return __builtin_bit_cast(uint32_t, s);
}

// ---- asm helpers: 64-bit VGPR pointer + off (proven operand pattern) -------

__device__ __forceinline__ uint32_t load1_sc0(const uint32_t* p) {
  uint32_t v;
  asm volatile("global_load_dword %0, %1, off sc0\n\t"
               "s_waitcnt vmcnt(0)"
               : "=&v"(v) : "v"(p) : "memory");
  return v;
}
__device__ __forceinline__ uint32_t load1_dev(const uint32_t* p) {
  uint32_t v;
  asm volatile("global_load_dword %0, %1, off sc0 sc1\n\t"
               "s_waitcnt vmcnt(0)"
               : "=&v"(v) : "v"(p) : "memory");
  return v;
}

__device__ __forceinline__ void load8_sc0(
    const uint32_t* p0, const uint32_t* p1, const uint32_t* p2, const uint32_t* p3,
    const uint32_t* p4, const uint32_t* p5, const uint32_t* p6, const uint32_t* p7,
    u32x4& v0, u32x4& v1, u32x4& v2, u32x4& v3,
    u32x4& v4, u32x4& v5, u32x4& v6, u32x4& v7) {
  asm volatile(
      "global_load_dwordx4 %0, %8, off sc0\n\t"
      "global_load_dwordx4 %1, %9, off sc0\n\t"
      "global_load_dwordx4 %2, %10, off sc0\n\t"
      "global_load_dwordx4 %3, %11, off sc0\n\t"
      "global_load_dwordx4 %4, %12, off sc0\n\t"
      "global_load_dwordx4 %5, %13, off sc0\n\t"
      "global_load_dwordx4 %6, %14, off sc0\n\t"
      "global_load_dwordx4 %7, %15, off sc0\n\t"
      "s_waitcnt vmcnt(0)"
      : "=&v"(v0), "=&v"(v1), "=&v"(v2), "=&v"(v3),
        "=&v"(v4), "=&v"(v5), "=&v"(v6), "=&v"(v7)
      : "v"(p0), "v"(p1), "v"(p2), "v"(p3), "v"(p4), "v"(p5), "v"(p6), "v"(p7)
      : "memory");
}

__device__ __forceinline__ void load8_dev(
    const uint32_t* p0, const uint32_t* p1, const uint32_t* p2, const uint32_t* p3,
    const uint32_t* p4, const uint32_t* p5, const uint32_t* p6, const uint32_t* p7,
    u32x4& v0, u32x4& v1, u32x4& v2, u32x4& v3,
    u32x4& v4, u32x4& v5, u32x4& v6, u32x4& v7) {
  asm volatile(
      "global_load_dwordx4 %0, %8, off sc0 sc1\n\t"
      "global_load_dwordx4 %1, %9, off sc0 sc1\n\t"
      "global_load_dwordx4 %2, %10, off sc0 sc1\n\t"
      "global_load_dwordx4 %3, %11, off sc0 sc1\n\t"
      "global_load_dwordx4 %4, %12, off sc0 sc1\n\t"
      "global_load_dwordx4 %5, %13, off sc0 sc1\n\t"
      "global_load_dwordx4 %6, %14, off sc0 sc1\n\t"
      "global_load_dwordx4 %7, %15, off sc0 sc1\n\t"
      "s_waitcnt vmcnt(0)"
      : "=&v"(v0), "=&v"(v1), "=&v"(v2), "=&v"(v3),
        "=&v"(v4), "=&v"(v5), "=&v"(v6), "=&v"(v7)
      : "v"(p0), "v"(p1), "v"(p2), "v"(p3), "v"(p4), "v"(p5), "v"(p6), "v"(p7)
      : "memory");
}

// Fire-and-forget u prefetch: NO waitcnt; consumed only after a counted
// s_waitcnt + sched_barrier(0).
__device__ __forceinline__ void issue_u4(
    const float* p0, const float* p1, const float* p2, const float* p3,
    float& d0, float& d1, float& d2, float& d3) {
  asm volatile(
      "global_load_dword %0, %4, off\n\t"
      "global_load_dword %1, %5, off\n\t"
      "global_load_dword %2, %6, off\n\t"
      "global_load_dword %3, %7, off"
      : "=&v"(d0), "=&v"(d1), "=&v"(d2), "=&v"(d3)
      : "v"(p0), "v"(p1), "v"(p2), "v"(p3)
      : "memory");
}

__device__ __forceinline__ void store4_plain(
    uint32_t* p0, uint32_t* p1, uint32_t* p2, uint32_t* p3,
    uint32_t d0, uint32_t d1, uint32_t d2, uint32_t d3) {
  asm volatile(
      "global_store_dword %4, %0, off\n\t"
      "global_store_dword %5, %1, off\n\t"
      "global_store_dword %6, %2, off\n\t"
      "global_store_dword %7, %3, off"
      :
      : "v"(d0), "v"(d1), "v"(d2), "v"(d3),
        "v"(p0), "v"(p1), "v"(p2), "v"(p3)
      : "memory");
}
__device__ __forceinline__ void store4_sc0s(
    uint32_t* p0, uint32_t* p1, uint32_t* p2, uint32_t* p3,
    uint32_t d0, uint32_t d1, uint32_t d2, uint32_t d3) {
  asm volatile(
      "global_store_dword %4, %0, off sc0\n\t"
      "global_store_dword %5, %1, off sc0\n\t"
      "global_store_dword %6, %2, off sc0\n\t"
      "global_store_dword %7, %3, off sc0"
      :
      : "v"(d0), "v"(d1), "v"(d2), "v"(d3),
        "v"(p0), "v"(p1), "v"(p2), "v"(p3)
      : "memory");
}
__device__ __forceinline__ void store4_dev(
    uint32_t* p0, uint32_t* p1, uint32_t* p2, uint32_t* p3,
    uint32_t d0, uint32_t d1, uint32_t d2, uint32_t d3) {
  asm volatile(
      "global_store_dword %4, %0, off sc0 sc1\n\t"
      "global_store_dword %5, %1, off sc0 sc1\n\t"
      "global_store_dword %6, %2, off sc0 sc1\n\t"
      "global_store_dword %7, %3, off sc0 sc1"
      :
      : "v"(d0), "v"(d1), "v"(d2), "v"(d3),
        "v"(p0), "v"(p1), "v"(p2), "v"(p3)
      : "memory");
}

// ---------------------------------------------------------------------------
// Phase 1: M=65536 (b*T+t), N=512 (h), K=128. 64x64 tile per WG.
__global__ __launch_bounds__(256) void phase1_gemm(const float* __restrict__ x,
                                                   const float* __restrict__ Wi,
                                                   const float* __restrict__ bi,
                                                   float* __restrict__ out) {
  const int tid  = threadIdx.x;
  const int wid  = tid >> 6;
  const int lane = tid & 63;
  const int quad = lane >> 4;
  const int mcol = lane & 15;
  const int r0 = blockIdx.y * 64 + wid * 16;
  const int h0 = blockIdx.x * 64;

  f32x4 acc[4] = {};
#pragma unroll
  for (int kk = 0; kk < 4; kk++) {
    const int k = kk * 32 + quad * 8;
    const f32x4* ap = (const f32x4*)(x + (size_t)(r0 + mcol) * NIN + k);
    f32x4 alo = ap[0], ahi = ap[1];
    half8 a;
#pragma unroll
    for (int j = 0; j < 4; j++) { a[j] = (_Float16)alo[j]; a[4 + j] = (_Float16)ahi[j]; }
#pragma unroll
    for (int nt = 0; nt < 4; nt++) {
      const f32x4* bp = (const f32x4*)(Wi + (size_t)(h0 + nt * 16 + mcol) * NIN + k);
      f32x4 blo = bp[0], bhi = bp[1];
      half8 b;
#pragma unroll
      for (int j = 0; j < 4; j++) { b[j] = (_Float16)blo[j]; b[4 + j] = (_Float16)bhi[j]; }
      acc[nt] = __builtin_amdgcn_mfma_f32_16x16x32_f16(a, b, acc[nt], 0, 0, 0);
    }
  }
#pragma unroll
  for (int nt = 0; nt < 4; nt++) {
    const int h = h0 + nt * 16 + mcol;
    const float bib = bi[h];
#pragma unroll
    for (int rr = 0; rr < 4; rr++) {
      const int r = r0 + quad * 4 + rr;
      out[(size_t)r * NHID + h] = tanh_fast(acc[nt][rr] + bib);
    }
  }
}

// ---------------------------------------------------------------------------
// Phase 2: persistent scan. Grid = 128 WGs x 256 threads.
__global__ __launch_bounds__(256, 1) void phase2_scan(const float* __restrict__ Wh,
                                                      const float* __restrict__ bh,
                                                      float* out, uint32_t* exch) {
  const int tid  = threadIdx.x;
  const int wid  = tid >> 6;
  const int lane = tid & 63;
  const int quad = lane >> 4;
  const int col  = lane & 15;
  const int wg = blockIdx.x;
  const int g  = wg & 7;   // XCD co-location heuristic (correctness-safe)
  const int w  = wg >> 3;
  const int b0 = g * 8;
  const int h0 = w * 32;

  __shared__ half8 WhF[2 * 16 * 64];            // 32 KB Wh fragments
  __shared__ __align__(16) uint32_t AF[4096];   // 16 KB swizzled state frags

  // ---- preload Wh[h0..h0+32) as f16 fragments; zero AF --------------------
  {
    const int lh = tid >> 3;          // 0..31 local h row
    const int k0 = (tid & 7) * 64;
    const int nt_ = lh >> 4, n_ = lh & 15;
    const float* src = Wh + (size_t)(h0 + lh) * NHID + k0;
#pragma unroll
    for (int c = 0; c < 8; c++) {
      const int k = k0 + c * 8;
      const f32x4* p = (const f32x4*)(src + c * 8);
      f32x4 lo = p[0], hi = p[1];
      half8 hb;
#pragma unroll
      for (int j = 0; j < 4; j++) { hb[j] = (_Float16)lo[j]; hb[4 + j] = (_Float16)hi[j]; }
      WhF[(nt_ * 16 + (k >> 5)) * 64 + ((k >> 3) & 3) * 16 + n_] = hb;
    }
    for (int i = tid; i < 4096; i += 256) AF[i] = 0;  // zero => t=0 state
  }
  __syncthreads();

  // ---- producer persistent state (waves 0,1) ------------------------------
  half8 WB[16];
  float bhv = 0.0f;
  if (wid < 2) {
#pragma unroll
    for (int kk = 0; kk < 16; kk++) WB[kk] = WhF[(wid * 16 + kk) * 64 + lane];
    bhv = bh[h0 + wid * 16 + col];
    __builtin_amdgcn_s_setprio(1);  // producers are the serial critical path
  }
  uint32_t a_off[16];  // swizzled AF fragment byte addresses (constant)
  {
    const uint32_t xr = (uint32_t)((lane & 7) << 4);
#pragma unroll
    for (int kk = 0; kk < 16; kk++)
      a_off[kk] = (uint32_t)((lane & 15) * 1024) +
                  (((uint32_t)(kk * 64 + quad * 16)) ^ xr);
  }

  // ---- consumer persistent state (waves 2,3) ------------------------------
  const int cj = (tid >= 128) ? (tid - 128) : 0;  // 0..127
  uint32_t wr_off[8];
#pragma unroll
  for (int i = 0; i < 8; i++)
    wr_off[i] = (uint32_t)(i * 1024) +
                (((uint32_t)(cj * 8)) ^ (uint32_t)(i << 4));
  uint32_t* const exg = exch + (size_t)g * 8192;  // fast group base (dwords)
  const uint32_t* pc[2][8];
#pragma unroll
  for (int s = 0; s < 2; s++)
#pragma unroll
    for (int i = 0; i < 8; i++)
      pc[s][i] = exg + s * 4096 + i * 512 + cj * 4;
  // probe map: lane covers slice (lane>>2), rows {0,2,4,6} -> all 16 slices
  // witnessed per wave; the bulk read verifies every word anyway.
  const uint32_t* pq[2];
#pragma unroll
  for (int s = 0; s < 2; s++) {
    const int prow = (lane & 3) * 2;
    const int ph   = (lane >> 2) * 32 + (lane & 3) * 4;
    pq[s] = exg + s * 4096 + prow * 512 + ph;
  }

  // ---- producer pointers (lanes quad<2 of waves 0,1) ----------------------
  const int hcol = h0 + wid * 16 + col;
  const int rb = quad * 4;
  uint32_t* pe[2][4];
#pragma unroll
  for (int s = 0; s < 2; s++)
#pragma unroll
    for (int r = 0; r < 4; r++)
      pe[s][r] = exg + s * 4096 + (rb + r) * 512 + hcol;
  const float* pu[4];  // next u load position (starts at t=0)
  uint32_t*    ps[4];  // next s store position (starts at t=0)
#pragma unroll
  for (int r = 0; r < 4; r++) {
    const size_t base = (size_t)(b0 + rb + r) * (T_STEPS * NHID) + hcol;
    pu[r] = out + base;
    ps[r] = (uint32_t*)(out + base);
  }

  // ---- peel t=0: s_0 = u_0 + tanh(bh) -------------------------------------
  float uA0 = 0, uA1 = 0, uA2 = 0, uA3 = 0;   // u for odd t
  float uB0 = 0, uB1 = 0, uB2 = 0, uB3 = 0;   // u for even t
  if (wid < 2 && quad < 2) {
    issue_u4(pu[0], pu[1], pu[2], pu[3], uB0, uB1, uB2, uB3);                 // u_0
    issue_u4(pu[0] + 512, pu[1] + 512, pu[2] + 512, pu[3] + 512,
             uA0, uA1, uA2, uA3);                                             // u_1
#pragma unroll
    for (int r = 0; r < 4; r++) pu[r] += 1024;  // next issue = t=2
    asm volatile("s_waitcnt vmcnt(4)" ::: "memory");  // u_0 retired
    __builtin_amdgcn_sched_barrier(0);
    const float tb = tanh_fast(bhv);
    const float s0 = uB0 + tb, s1 = uB1 + tb, s2 = uB2 + tb, s3 = uB3 + tb;
    const uint32_t tg1 = 1u << 16;
    const uint32_t w0 = tg1 | f16b(s0), w1 = tg1 | f16b(s1),
                   w2 = tg1 | f16b(s2), w3 = tg1 | f16b(s3);
    store4_sc0s(pe[0][0], pe[0][1], pe[0][2], pe[0][3], w0, w1, w2, w3);
    store4_dev (pe[0][0] + SLOW_OFF, pe[0][1] + SLOW_OFF,
                pe[0][2] + SLOW_OFF, pe[0][3] + SLOW_OFF, w0, w1, w2, w3);
    store4_plain(ps[0], ps[1], ps[2], ps[3],
                 fbits(s0), fbits(s1), fbits(s2), fbits(s3));
#pragma unroll
    for (int r = 0; r < 4; r++) ps[r] += 512;   // next s store = t=1
  }

  // ---- main loop: one raw barrier per step, counted vmcnt -----------------
  auto body = [&](int t, int sp /*poll slot, compile-time at call site*/,
                  float& c0, float& c1, float& c2, float& c3,
                  float& n0, float& n1, float& n2, float& n3) {
    if (wid >= 2) {
      // poll s_{t-1} (slot sp, tag t): sc0 fast path (L2-resident fast
      // buffer), device-scope slow-mirror fallback every 4th try
      // (placement-independent correctness).
      const uint32_t tg = (uint32_t)t << 16;
      // -- stage 1: tiny probe spin (64 words/wave, all 16 slices) --
      {
        int tries = 0;
        for (;;) {
          uint32_t v;
          if ((tries & 3) != 3) v = load1_sc0(pq[sp]);
          else                  v = load1_dev(pq[sp] + SLOW_OFF);
          if (!__any((int)((v ^ tg) & 0xFFFF0000u))) break;
          if (++tries > 64) __builtin_amdgcn_s_sleep(1);
        }
      }
      // -- stage 2: bulk verified read (normally a single pass) --
      u32x4 v0, v1, v2, v3, v4, v5, v6, v7;
      int btries = 0;
      for (;;) {
        if ((btries & 3) != 3)
          load8_sc0(pc[sp][0], pc[sp][1], pc[sp][2], pc[sp][3],
                    pc[sp][4], pc[sp][5], pc[sp][6], pc[sp][7],
                    v0, v1, v2, v3, v4, v5, v6, v7);
        else
          load8_dev(pc[sp][0] + SLOW_OFF, pc[sp][1] + SLOW_OFF,
                    pc[sp][2] + SLOW_OFF, pc[sp][3] + SLOW_OFF,
                    pc[sp][4] + SLOW_OFF, pc[sp][5] + SLOW_OFF,
                    pc[sp][6] + SLOW_OFF, pc[sp][7] + SLOW_OFF,
                    v0, v1, v2, v3, v4, v5, v6, v7);
        uint32_t bad = (v0[0] ^ tg) | (v0[1] ^ tg) | (v0[2] ^ tg) | (v0[3] ^ tg);
        bad |= (v1[0] ^ tg) | (v1[1] ^ tg) | (v1[2] ^ tg) | (v1[3] ^ tg);
        bad |= (v2[0] ^ tg) | (v2[1] ^ tg) | (v2[2] ^ tg) | (v2[3] ^ tg);
        bad |= (v3[0] ^ tg) | (v3[1] ^ tg) | (v3[2] ^ tg) | (v3[3] ^ tg);
        bad |= (v4[0] ^ tg) | (v4[1] ^ tg) | (v4[2] ^ tg) | (v4[3] ^ tg);
        bad |= (v5[0] ^ tg) | (v5[1] ^ tg) | (v5[2] ^ tg) | (v5[3] ^ tg);
        bad |= (v6[0] ^ tg) | (v6[1] ^ tg) | (v6[2] ^ tg) | (v6[3] ^ tg);
        bad |= (v7[0] ^ tg) | (v7[1] ^ tg) | (v7[2] ^ tg) | (v7[3] ^ tg);
        if (!(bad & 0xFFFF0000u)) break;
        if (++btries > 64) __builtin_amdgcn_s_sleep(1);
      }
      char* afc = (char*)AF;
#define UNPK(i, V)                                                        \
      {                                                                   \
        uint32_t plo = ((V)[1] << 16) | ((V)[0] & 0xFFFFu);               \
        uint32_t phi = ((V)[3] << 16) | ((V)[2] & 0xFFFFu);               \
        *(uint64_t*)(afc + wr_off[i]) = ((uint64_t)phi << 32) | plo;      \
      }
      UNPK(0, v0) UNPK(1, v1) UNPK(2, v2) UNPK(3, v3)
      UNPK(4, v4) UNPK(5, v5) UNPK(6, v6) UNPK(7, v7)
#undef UNPK
    } else if (quad < 2) {
      // issue u_{t+1}; at t=T-1 this reads the (valid) `last` region and is
      // discarded -- keeps the vmcnt accounting uniform.
      issue_u4(pu[0], pu[1], pu[2], pu[3], n0, n1, n2, n3);
#pragma unroll
      for (int r = 0; r < 4; r++) pu[r] += 512;
    }
    // the ONLY barrier per step: LDS drain only; global ops stay in flight
    asm volatile("s_waitcnt lgkmcnt(0)" ::: "memory");
    __builtin_amdgcn_s_barrier();
    asm volatile("" ::: "memory");
    if (wid < 2) {
      const char* afc = (const char*)AF;
      f32x4 A0 = {0.f, 0.f, 0.f, 0.f}, A1 = {0.f, 0.f, 0.f, 0.f};
#pragma unroll
      for (int kk = 0; kk < 16; kk += 2) {  // two independent MFMA chains
        half8 x0 = *(const half8*)(afc + a_off[kk]);
        half8 x1 = *(const half8*)(afc + a_off[kk + 1]);
        A0 = __builtin_amdgcn_mfma_f32_16x16x32_f16(x0, WB[kk], A0, 0, 0, 0);
        A1 = __builtin_amdgcn_mfma_f32_16x16x32_f16(x1, WB[kk + 1], A1, 0, 0, 0);
      }
      if (quad < 2) {
        // Younger than u_t at this point: 12 stores (step t-1) + 4 u_{t+1}
        // loads = 16; in-order vmcnt retirement => u_t is retired.
        asm volatile("s_waitcnt vmcnt(16)" ::: "memory");
        __builtin_amdgcn_sched_barrier(0);
        const float s0 = c0 + tanh_fast(A0[0] + A1[0] + bhv);
        const float s1 = c1 + tanh_fast(A0[1] + A1[1] + bhv);
        const float s2 = c2 + tanh_fast(A0[2] + A1[2] + bhv);
        const float s3 = c3 + tanh_fast(A0[3] + A1[3] + bhv);
        const uint32_t tg1 = (uint32_t)(t + 1) << 16;
        const uint32_t w0 = tg1 | f16b(s0), w1 = tg1 | f16b(s1),
                       w2 = tg1 | f16b(s2), w3 = tg1 | f16b(s3);
        const int pb = sp ^ 1;  // publish slot = t&1
        store4_sc0s(pe[pb][0], pe[pb][1], pe[pb][2], pe[pb][3], w0, w1, w2, w3);
        store4_dev (pe[pb][0] + SLOW_OFF, pe[pb][1] + SLOW_OFF,
                    pe[pb][2] + SLOW_OFF, pe[pb][3] + SLOW_OFF, w0, w1, w2, w3);
        store4_plain(ps[0], ps[1], ps[2], ps[3],
                     fbits(s0), fbits(s1), fbits(s2), fbits(s3));
#pragma unroll
        for (int r = 0; r < 4; r++) ps[r] += 512;
        if (t == T_STEPS - 1) {
          uint32_t* q0 = (uint32_t*)(out + (size_t)STATES_ELEMS + (size_t)(b0 + rb + 0) * NHID + hcol);
          uint32_t* q1 = (uint32_t*)(out + (size_t)STATES_ELEMS + (size_t)(b0 + rb + 1) * NHID + hcol);
          uint32_t* q2 = (uint32_t*)(out + (size_t)STATES_ELEMS + (size_t)(b0 + rb + 2) * NHID + hcol);
          uint32_t* q3 = (uint32_t*)(out + (size_t)STATES_ELEMS + (size_t)(b0 + rb + 3) * NHID + hcol);
          store4_plain(q0, q1, q2, q3, fbits(s0), fbits(s1), fbits(s2), fbits(s3));
        }
      }
    }
  };

#pragma unroll 1
  for (int t = 1; t < T_STEPS; t += 2) {
    body(t, 0, uA0, uA1, uA2, uA3, uB0, uB1, uB2, uB3);
    if (t + 1 < T_STEPS)
      body(t + 1, 1, uB0, uB1, uB2, uB3, uA0, uA1, uA2, uA3);
  }
}

// ---------------------------------------------------------------------------
extern "C" void kernel_launch(void* const* d_in, const int* in_sizes, int n_in,
                              void* d_out, int out_size, void* d_ws, size_t ws_size,
                              hipStream_t stream) {
  const float* x  = (const float*)d_in[0];
  const float* Wi = (const float*)d_in[1];
  const float* bi = (const float*)d_in[2];
  const float* Wh = (const float*)d_in[3];
  const float* bh = (const float*)d_in[4];
  float* out = (float*)d_out;
  uint32_t* exch = (uint32_t*)d_ws;  // 512 KB: fast [0,256K) + slow [256K,512K)

  hipLaunchKernelGGL(phase1_gemm, dim3(8, 1024), dim3(256), 0, stream, x, Wi, bi, out);
  hipLaunchKernelGGL(phase2_scan, dim3(128), dim3(256), 0, stream, Wh, bh, out, exch);
}

// Round 8
// 2499.313 us; speedup vs baseline: 1.5786x; 1.5786x over previous
//
#include <hip/hip_runtime.h>
#include <stdint.h>

// ---------------------------------------------------------------------------
// RNN scan, fp32. Phase 1: u = tanh(x@Wi^T+bi) into states region.
// Phase 2: persistent scan, 8 groups (8 batches) x 16 h-slices (32 h).
//   ROUND 8 = round-7 (split fast/slow buffers) + runtime XCD-based group
//   formation. Seven rounds of evidence: g=wg&7 co-location NEVER held
//   (R7: sc0-only fast path slowest of all -> consumers poll stale remote-L2
//   lines forever; R3 only worked because its same-address sc1 write-through
//   invalidated remote L2 copies, dropping polls to L3 latency).
//   NEW: each WG reads its physical XCD via s_getreg(HW_REG_XCC_ID), 
//   registers in a d_ws registry (zeroed by phase1; kernel-boundary makes it
//   visible), rendezvouses, and forms groups BY PHYSICAL XCD: g=xcd,
//   w=arrival order. Overflow WGs deterministically adopt missing slots ->
//   correctness independent of dispatch; adoptees are rescued by the slow
//   mirror (alternating dev fallback). With true co-location the fast sc0
//   buffer lives in the group's SHARED XCD L2: no staleness possible
//   (sc0 bypasses L1; L2 is common), ~250cy RTT instead of 600-900.
//   Everything else identical to round 7 (probe->bulk polling, tagged words
//   carry all correctness, wave role split, one raw barrier per step,
//   counted vmcnt, swizzled AF). ws = 512 KB + 64 B registry (guarded:
//   falls back to static mapping if ws too small).
// ---------------------------------------------------------------------------

typedef _Float16 half8 __attribute__((ext_vector_type(8)));
typedef float    f32x4 __attribute__((ext_vector_type(4)));
typedef uint32_t u32x4 __attribute__((ext_vector_type(4)));

#define T_STEPS 1024
#define NHID    512
#define NIN     128
#define NBATCH  64
#define STATES_ELEMS (NBATCH * T_STEPS * NHID)  // 33554432
#define SLOW_OFF 65536                          // dwords: fast -> slow mirror
// s_getreg imm: id=20 (HW_REG_XCC_ID), offset=0, size=32 -> (31<<11)|20
#define XCC_ID_IMM 63508

__device__ __forceinline__ float tanh_fast(float x) {
  float e = __expf(2.0f * x);
  return 1.0f - 2.0f * __builtin_amdgcn_rcpf(e + 1.0f);
}
__device__ __forceinline__ uint32_t f16b(float s) {
  return (uint32_t)__builtin_bit_cast(unsigned short, (_Float16)s);
}
__device__ __forceinline__ uint32_t fbits(float s) {
  return __builtin_bit_cast(uint32_t, s);
}

// ---- asm helpers: 64-bit VGPR pointer + off (proven operand pattern) -------

__device__ __forceinline__ uint32_t load1_sc0(const uint32_t* p) {
  uint32_t v;
  asm volatile("global_load_dword %0, %1, off sc0\n\t"
               "s_waitcnt vmcnt(0)"
               : "=&v"(v) : "v"(p) : "memory");
  return v;
}
__device__ __forceinline__ uint32_t load1_dev(const uint32_t* p) {
  uint32_t v;
  asm volatile("global_load_dword %0, %1, off sc0 sc1\n\t"
               "s_waitcnt vmcnt(0)"
               : "=&v"(v) : "v"(p) : "memory");
  return v;
}

__device__ __forceinline__ void load8_sc0(
    const uint32_t* p0, const uint32_t* p1, const uint32_t* p2, const uint32_t* p3,
    const uint32_t* p4, const uint32_t* p5, const uint32_t* p6, const uint32_t* p7,
    u32x4& v0, u32x4& v1, u32x4& v2, u32x4& v3,
    u32x4& v4, u32x4& v5, u32x4& v6, u32x4& v7) {
  asm volatile(
      "global_load_dwordx4 %0, %8, off sc0\n\t"
      "global_load_dwordx4 %1, %9, off sc0\n\t"
      "global_load_dwordx4 %2, %10, off sc0\n\t"
      "global_load_dwordx4 %3, %11, off sc0\n\t"
      "global_load_dwordx4 %4, %12, off sc0\n\t"
      "global_load_dwordx4 %5, %13, off sc0\n\t"
      "global_load_dwordx4 %6, %14, off sc0\n\t"
      "global_load_dwordx4 %7, %15, off sc0\n\t"
      "s_waitcnt vmcnt(0)"
      : "=&v"(v0), "=&v"(v1), "=&v"(v2), "=&v"(v3),
        "=&v"(v4), "=&v"(v5), "=&v"(v6), "=&v"(v7)
      : "v"(p0), "v"(p1), "v"(p2), "v"(p3), "v"(p4), "v"(p5), "v"(p6), "v"(p7)
      : "memory");
}

__device__ __forceinline__ void load8_dev(
    const uint32_t* p0, const uint32_t* p1, const uint32_t* p2, const uint32_t* p3,
    const uint32_t* p4, const uint32_t* p5, const uint32_t* p6, const uint32_t* p7,
    u32x4& v0, u32x4& v1, u32x4& v2, u32x4& v3,
    u32x4& v4, u32x4& v5, u32x4& v6, u32x4& v7) {
  asm volatile(
      "global_load_dwordx4 %0, %8, off sc0 sc1\n\t"
      "global_load_dwordx4 %1, %9, off sc0 sc1\n\t"
      "global_load_dwordx4 %2, %10, off sc0 sc1\n\t"
      "global_load_dwordx4 %3, %11, off sc0 sc1\n\t"
      "global_load_dwordx4 %4, %12, off sc0 sc1\n\t"
      "global_load_dwordx4 %5, %13, off sc0 sc1\n\t"
      "global_load_dwordx4 %6, %14, off sc0 sc1\n\t"
      "global_load_dwordx4 %7, %15, off sc0 sc1\n\t"
      "s_waitcnt vmcnt(0)"
      : "=&v"(v0), "=&v"(v1), "=&v"(v2), "=&v"(v3),
        "=&v"(v4), "=&v"(v5), "=&v"(v6), "=&v"(v7)
      : "v"(p0), "v"(p1), "v"(p2), "v"(p3), "v"(p4), "v"(p5), "v"(p6), "v"(p7)
      : "memory");
}

// Fire-and-forget u prefetch: NO waitcnt; consumed only after a counted
// s_waitcnt + sched_barrier(0).
__device__ __forceinline__ void issue_u4(
    const float* p0, const float* p1, const float* p2, const float* p3,
    float& d0, float& d1, float& d2, float& d3) {
  asm volatile(
      "global_load_dword %0, %4, off\n\t"
      "global_load_dword %1, %5, off\n\t"
      "global_load_dword %2, %6, off\n\t"
      "global_load_dword %3, %7, off"
      : "=&v"(d0), "=&v"(d1), "=&v"(d2), "=&v"(d3)
      : "v"(p0), "v"(p1), "v"(p2), "v"(p3)
      : "memory");
}

__device__ __forceinline__ void store4_plain(
    uint32_t* p0, uint32_t* p1, uint32_t* p2, uint32_t* p3,
    uint32_t d0, uint32_t d1, uint32_t d2, uint32_t d3) {
  asm volatile(
      "global_store_dword %4, %0, off\n\t"
      "global_store_dword %5, %1, off\n\t"
      "global_store_dword %6, %2, off\n\t"
      "global_store_dword %7, %3, off"
      :
      : "v"(d0), "v"(d1), "v"(d2), "v"(d3),
        "v"(p0), "v"(p1), "v"(p2), "v"(p3)
      : "memory");
}
__device__ __forceinline__ void store4_sc0s(
    uint32_t* p0, uint32_t* p1, uint32_t* p2, uint32_t* p3,
    uint32_t d0, uint32_t d1, uint32_t d2, uint32_t d3) {
  asm volatile(
      "global_store_dword %4, %0, off sc0\n\t"
      "global_store_dword %5, %1, off sc0\n\t"
      "global_store_dword %6, %2, off sc0\n\t"
      "global_store_dword %7, %3, off sc0"
      :
      : "v"(d0), "v"(d1), "v"(d2), "v"(d3),
        "v"(p0), "v"(p1), "v"(p2), "v"(p3)
      : "memory");
}
__device__ __forceinline__ void store4_dev(
    uint32_t* p0, uint32_t* p1, uint32_t* p2, uint32_t* p3,
    uint32_t d0, uint32_t d1, uint32_t d2, uint32_t d3) {
  asm volatile(
      "global_store_dword %4, %0, off sc0 sc1\n\t"
      "global_store_dword %5, %1, off sc0 sc1\n\t"
      "global_store_dword %6, %2, off sc0 sc1\n\t"
      "global_store_dword %7, %3, off sc0 sc1"
      :
      : "v"(d0), "v"(d1), "v"(d2), "v"(d3),
        "v"(p0), "v"(p1), "v"(p2), "v"(p3)
      : "memory");
}

// ---------------------------------------------------------------------------
// Phase 1: M=65536 (b*T+t), N=512 (h), K=128. 64x64 tile per WG.
// Also zeroes the phase-2 registry (visible at kernel boundary).
__global__ __launch_bounds__(256) void phase1_gemm(const float* __restrict__ x,
                                                   const float* __restrict__ Wi,
                                                   const float* __restrict__ bi,
                                                   float* __restrict__ out,
                                                   uint32_t* reg) {
  if (reg && blockIdx.x == 0 && blockIdx.y == 0 && threadIdx.x < 16)
    reg[threadIdx.x] = 0;

  const int tid  = threadIdx.x;
  const int wid  = tid >> 6;
  const int lane = tid & 63;
  const int quad = lane >> 4;
  const int mcol = lane & 15;
  const int r0 = blockIdx.y * 64 + wid * 16;
  const int h0 = blockIdx.x * 64;

  f32x4 acc[4] = {};
#pragma unroll
  for (int kk = 0; kk < 4; kk++) {
    const int k = kk * 32 + quad * 8;
    const f32x4* ap = (const f32x4*)(x + (size_t)(r0 + mcol) * NIN + k);
    f32x4 alo = ap[0], ahi = ap[1];
    half8 a;
#pragma unroll
    for (int j = 0; j < 4; j++) { a[j] = (_Float16)alo[j]; a[4 + j] = (_Float16)ahi[j]; }
#pragma unroll
    for (int nt = 0; nt < 4; nt++) {
      const f32x4* bp = (const f32x4*)(Wi + (size_t)(h0 + nt * 16 + mcol) * NIN + k);
      f32x4 blo = bp[0], bhi = bp[1];
      half8 b;
#pragma unroll
      for (int j = 0; j < 4; j++) { b[j] = (_Float16)blo[j]; b[4 + j] = (_Float16)bhi[j]; }
      acc[nt] = __builtin_amdgcn_mfma_f32_16x16x32_f16(a, b, acc[nt], 0, 0, 0);
    }
  }
#pragma unroll
  for (int nt = 0; nt < 4; nt++) {
    const int h = h0 + nt * 16 + mcol;
    const float bib = bi[h];
#pragma unroll
    for (int rr = 0; rr < 4; rr++) {
      const int r = r0 + quad * 4 + rr;
      out[(size_t)r * NHID + h] = tanh_fast(acc[nt][rr] + bib);
    }
  }
}

// ---------------------------------------------------------------------------
// Phase 2: persistent scan. Grid = 128 WGs x 256 threads.
__global__ __launch_bounds__(256, 1) void phase2_scan(const float* __restrict__ Wh,
                                                      const float* __restrict__ bh,
                                                      float* out, uint32_t* exch,
                                                      uint32_t* reg) {
  const int tid  = threadIdx.x;
  const int wid  = tid >> 6;
  const int lane = tid & 63;
  const int quad = lane >> 4;
  const int col  = lane & 15;
  const int wg = blockIdx.x;

  // ---- runtime XCD-based group formation ----------------------------------
  __shared__ int s_role;
  int g_, w_;
  if (reg != nullptr) {
    if (tid == 0) {
      const uint32_t xcd = __builtin_amdgcn_s_getreg(XCC_ID_IMM) & 7u;
      const uint32_t pos = atomicAdd(&reg[xcd], 1u);
      asm volatile("s_waitcnt vmcnt(0)" ::: "memory");  // cnt-add performed
      atomicAdd(&reg[8], 1u);
      int spin = 0;
      for (;;) {  // rendezvous: all 128 WGs registered
        const uint32_t done = atomicAdd(&reg[8], 0u);
        if (done >= 128u) break;
        if (++spin > 256) __builtin_amdgcn_s_sleep(2);
      }
      int gg, ww;
      if (pos < 16u) {
        gg = (int)xcd; ww = (int)pos;
      } else {
        uint32_t cnt[8];
#pragma unroll
        for (int i = 0; i < 8; i++) cnt[i] = atomicAdd(&reg[i], 0u);
        int myov = (int)(pos - 16u);
        for (int x = 0; x < (int)xcd; x++)
          myov += (cnt[x] > 16u) ? (int)(cnt[x] - 16u) : 0;
        int k = myov; gg = 0; ww = 0;
        for (int x = 0; x < 8; x++) {
          const int miss = (cnt[x] < 16u) ? (int)(16u - cnt[x]) : 0;
          if (k < miss) { gg = x; ww = (int)cnt[x] + k; break; }
          k -= miss;
        }
      }
      s_role = gg * 16 + ww;
    }
    __syncthreads();
    g_ = s_role >> 4; w_ = s_role & 15;
  } else {
    g_ = wg & 7; w_ = wg >> 3;   // static fallback (round-7 behavior)
  }
  const int g = g_;
  const int w = w_;
  const int b0 = g * 8;
  const int h0 = w * 32;

  __shared__ half8 WhF[2 * 16 * 64];            // 32 KB Wh fragments
  __shared__ __align__(16) uint32_t AF[4096];   // 16 KB swizzled state frags

  // ---- preload Wh[h0..h0+32) as f16 fragments; zero AF --------------------
  {
    const int lh = tid >> 3;          // 0..31 local h row
    const int k0 = (tid & 7) * 64;
    const int nt_ = lh >> 4, n_ = lh & 15;
    const float* src = Wh + (size_t)(h0 + lh) * NHID + k0;
#pragma unroll
    for (int c = 0; c < 8; c++) {
      const int k = k0 + c * 8;
      const f32x4* p = (const f32x4*)(src + c * 8);
      f32x4 lo = p[0], hi = p[1];
      half8 hb;
#pragma unroll
      for (int j = 0; j < 4; j++) { hb[j] = (_Float16)lo[j]; hb[4 + j] = (_Float16)hi[j]; }
      WhF[(nt_ * 16 + (k >> 5)) * 64 + ((k >> 3) & 3) * 16 + n_] = hb;
    }
    for (int i = tid; i < 4096; i += 256) AF[i] = 0;  // zero => t=0 state
  }
  __syncthreads();

  // ---- producer persistent state (waves 0,1) ------------------------------
  half8 WB[16];
  float bhv = 0.0f;
  if (wid < 2) {
#pragma unroll
    for (int kk = 0; kk < 16; kk++) WB[kk] = WhF[(wid * 16 + kk) * 64 + lane];
    bhv = bh[h0 + wid * 16 + col];
    __builtin_amdgcn_s_setprio(1);  // producers are the serial critical path
  }
  uint32_t a_off[16];  // swizzled AF fragment byte addresses (constant)
  {
    const uint32_t xr = (uint32_t)((lane & 7) << 4);
#pragma unroll
    for (int kk = 0; kk < 16; kk++)
      a_off[kk] = (uint32_t)((lane & 15) * 1024) +
                  (((uint32_t)(kk * 64 + quad * 16)) ^ xr);
  }

  // ---- consumer persistent state (waves 2,3) ------------------------------
  const int cj = (tid >= 128) ? (tid - 128) : 0;  // 0..127
  uint32_t wr_off[8];
#pragma unroll
  for (int i = 0; i < 8; i++)
    wr_off[i] = (uint32_t)(i * 1024) +
                (((uint32_t)(cj * 8)) ^ (uint32_t)(i << 4));
  uint32_t* const exg = exch + (size_t)g * 8192;  // fast group base (dwords)
  const uint32_t* pc[2][8];
#pragma unroll
  for (int s = 0; s < 2; s++)
#pragma unroll
    for (int i = 0; i < 8; i++)
      pc[s][i] = exg + s * 4096 + i * 512 + cj * 4;
  // probe map: lane covers slice (lane>>2), rows {0,2,4,6} -> all 16 slices
  // witnessed per wave; the bulk read verifies every word anyway.
  const uint32_t* pq[2];
#pragma unroll
  for (int s = 0; s < 2; s++) {
    const int prow = (lane & 3) * 2;
    const int ph   = (lane >> 2) * 32 + (lane & 3) * 4;
    pq[s] = exg + s * 4096 + prow * 512 + ph;
  }

  // ---- producer pointers (lanes quad<2 of waves 0,1) ----------------------
  const int hcol = h0 + wid * 16 + col;
  const int rb = quad * 4;
  uint32_t* pe[2][4];
#pragma unroll
  for (int s = 0; s < 2; s++)
#pragma unroll
    for (int r = 0; r < 4; r++)
      pe[s][r] = exg + s * 4096 + (rb + r) * 512 + hcol;
  const float* pu[4];  // next u load position (starts at t=0)
  uint32_t*    ps[4];  // next s store position (starts at t=0)
#pragma unroll
  for (int r = 0; r < 4; r++) {
    const size_t base = (size_t)(b0 + rb + r) * (T_STEPS * NHID) + hcol;
    pu[r] = out + base;
    ps[r] = (uint32_t*)(out + base);
  }

  // ---- peel t=0: s_0 = u_0 + tanh(bh) -------------------------------------
  float uA0 = 0, uA1 = 0, uA2 = 0, uA3 = 0;   // u for odd t
  float uB0 = 0, uB1 = 0, uB2 = 0, uB3 = 0;   // u for even t
  if (wid < 2 && quad < 2) {
    issue_u4(pu[0], pu[1], pu[2], pu[3], uB0, uB1, uB2, uB3);                 // u_0
    issue_u4(pu[0] + 512, pu[1] + 512, pu[2] + 512, pu[3] + 512,
             uA0, uA1, uA2, uA3);                                             // u_1
#pragma unroll
    for (int r = 0; r < 4; r++) pu[r] += 1024;  // next issue = t=2
    asm volatile("s_waitcnt vmcnt(4)" ::: "memory");  // u_0 retired
    __builtin_amdgcn_sched_barrier(0);
    const float tb = tanh_fast(bhv);
    const float s0 = uB0 + tb, s1 = uB1 + tb, s2 = uB2 + tb, s3 = uB3 + tb;
    const uint32_t tg1 = 1u << 16;
    const uint32_t w0 = tg1 | f16b(s0), w1 = tg1 | f16b(s1),
                   w2 = tg1 | f16b(s2), w3 = tg1 | f16b(s3);
    store4_sc0s(pe[0][0], pe[0][1], pe[0][2], pe[0][3], w0, w1, w2, w3);
    store4_dev (pe[0][0] + SLOW_OFF, pe[0][1] + SLOW_OFF,
                pe[0][2] + SLOW_OFF, pe[0][3] + SLOW_OFF, w0, w1, w2, w3);
    store4_plain(ps[0], ps[1], ps[2], ps[3],
                 fbits(s0), fbits(s1), fbits(s2), fbits(s3));
#pragma unroll
    for (int r = 0; r < 4; r++) ps[r] += 512;   // next s store = t=1
  }

  // ---- main loop: one raw barrier per step, counted vmcnt -----------------
  auto body = [&](int t, int sp /*poll slot, compile-time at call site*/,
                  float& c0, float& c1, float& c2, float& c3,
                  float& n0, float& n1, float& n2, float& n3) {
    if (wid >= 2) {
      // poll s_{t-1} (slot sp, tag t): sc0 fast path (shared XCD L2),
      // device-scope slow-mirror fallback every other try (rescues
      // cross-XCD adoptee slices; placement-independent correctness).
      const uint32_t tg = (uint32_t)t << 16;
      // -- stage 1: tiny probe spin (64 words/wave, all 16 slices) --
      {
        int tries = 0;
        for (;;) {
          uint32_t v;
          if ((tries & 1) == 0) v = load1_sc0(pq[sp]);
          else                  v = load1_dev(pq[sp] + SLOW_OFF);
          if (!__any((int)((v ^ tg) & 0xFFFF0000u))) break;
          if (++tries > 64) __builtin_amdgcn_s_sleep(1);
        }
      }
      // -- stage 2: bulk verified read (normally a single pass) --
      u32x4 v0, v1, v2, v3, v4, v5, v6, v7;
      int btries = 0;
      for (;;) {
        if ((btries & 1) == 0)
          load8_sc0(pc[sp][0], pc[sp][1], pc[sp][2], pc[sp][3],
                    pc[sp][4], pc[sp][5], pc[sp][6], pc[sp][7],
                    v0, v1, v2, v3, v4, v5, v6, v7);
        else
          load8_dev(pc[sp][0] + SLOW_OFF, pc[sp][1] + SLOW_OFF,
                    pc[sp][2] + SLOW_OFF, pc[sp][3] + SLOW_OFF,
                    pc[sp][4] + SLOW_OFF, pc[sp][5] + SLOW_OFF,
                    pc[sp][6] + SLOW_OFF, pc[sp][7] + SLOW_OFF,
                    v0, v1, v2, v3, v4, v5, v6, v7);
        uint32_t bad = (v0[0] ^ tg) | (v0[1] ^ tg) | (v0[2] ^ tg) | (v0[3] ^ tg);
        bad |= (v1[0] ^ tg) | (v1[1] ^ tg) | (v1[2] ^ tg) | (v1[3] ^ tg);
        bad |= (v2[0] ^ tg) | (v2[1] ^ tg) | (v2[2] ^ tg) | (v2[3] ^ tg);
        bad |= (v3[0] ^ tg) | (v3[1] ^ tg) | (v3[2] ^ tg) | (v3[3] ^ tg);
        bad |= (v4[0] ^ tg) | (v4[1] ^ tg) | (v4[2] ^ tg) | (v4[3] ^ tg);
        bad |= (v5[0] ^ tg) | (v5[1] ^ tg) | (v5[2] ^ tg) | (v5[3] ^ tg);
        bad |= (v6[0] ^ tg) | (v6[1] ^ tg) | (v6[2] ^ tg) | (v6[3] ^ tg);
        bad |= (v7[0] ^ tg) | (v7[1] ^ tg) | (v7[2] ^ tg) | (v7[3] ^ tg);
        if (!(bad & 0xFFFF0000u)) break;
        if (++btries > 64) __builtin_amdgcn_s_sleep(1);
      }
      char* afc = (char*)AF;
#define UNPK(i, V)                                                        \
      {                                                                   \
        uint32_t plo = ((V)[1] << 16) | ((V)[0] & 0xFFFFu);               \
        uint32_t phi = ((V)[3] << 16) | ((V)[2] & 0xFFFFu);               \
        *(uint64_t*)(afc + wr_off[i]) = ((uint64_t)phi << 32) | plo;      \
      }
      UNPK(0, v0) UNPK(1, v1) UNPK(2, v2) UNPK(3, v3)
      UNPK(4, v4) UNPK(5, v5) UNPK(6, v6) UNPK(7, v7)
#undef UNPK
    } else if (quad < 2) {
      // issue u_{t+1}; at t=T-1 this reads the (valid) `last` region and is
      // discarded -- keeps the vmcnt accounting uniform.
      issue_u4(pu[0], pu[1], pu[2], pu[3], n0, n1, n2, n3);
#pragma unroll
      for (int r = 0; r < 4; r++) pu[r] += 512;
    }
    // the ONLY barrier per step: LDS drain only; global ops stay in flight
    asm volatile("s_waitcnt lgkmcnt(0)" ::: "memory");
    __builtin_amdgcn_s_barrier();
    asm volatile("" ::: "memory");
    if (wid < 2) {
      const char* afc = (const char*)AF;
      f32x4 A0 = {0.f, 0.f, 0.f, 0.f}, A1 = {0.f, 0.f, 0.f, 0.f};
#pragma unroll
      for (int kk = 0; kk < 16; kk += 2) {  // two independent MFMA chains
        half8 x0 = *(const half8*)(afc + a_off[kk]);
        half8 x1 = *(const half8*)(afc + a_off[kk + 1]);
        A0 = __builtin_amdgcn_mfma_f32_16x16x32_f16(x0, WB[kk], A0, 0, 0, 0);
        A1 = __builtin_amdgcn_mfma_f32_16x16x32_f16(x1, WB[kk + 1], A1, 0, 0, 0);
      }
      if (quad < 2) {
        // Younger than u_t at this point: 12 stores (step t-1) + 4 u_{t+1}
        // loads = 16; in-order vmcnt retirement => u_t is retired.
        asm volatile("s_waitcnt vmcnt(16)" ::: "memory");
        __builtin_amdgcn_sched_barrier(0);
        const float s0 = c0 + tanh_fast(A0[0] + A1[0] + bhv);
        const float s1 = c1 + tanh_fast(A0[1] + A1[1] + bhv);
        const float s2 = c2 + tanh_fast(A0[2] + A1[2] + bhv);
        const float s3 = c3 + tanh_fast(A0[3] + A1[3] + bhv);
        const uint32_t tg1 = (uint32_t)(t + 1) << 16;
        const uint32_t w0 = tg1 | f16b(s0), w1 = tg1 | f16b(s1),
                       w2 = tg1 | f16b(s2), w3 = tg1 | f16b(s3);
        const int pb = sp ^ 1;  // publish slot = t&1
        store4_sc0s(pe[pb][0], pe[pb][1], pe[pb][2], pe[pb][3], w0, w1, w2, w3);
        store4_dev (pe[pb][0] + SLOW_OFF, pe[pb][1] + SLOW_OFF,
                    pe[pb][2] + SLOW_OFF, pe[pb][3] + SLOW_OFF, w0, w1, w2, w3);
        store4_plain(ps[0], ps[1], ps[2], ps[3],
                     fbits(s0), fbits(s1), fbits(s2), fbits(s3));
#pragma unroll
        for (int r = 0; r < 4; r++) ps[r] += 512;
        if (t == T_STEPS - 1) {
          uint32_t* q0 = (uint32_t*)(out + (size_t)STATES_ELEMS + (size_t)(b0 + rb + 0) * NHID + hcol);
          uint32_t* q1 = (uint32_t*)(out + (size_t)STATES_ELEMS + (size_t)(b0 + rb + 1) * NHID + hcol);
          uint32_t* q2 = (uint32_t*)(out + (size_t)STATES_ELEMS + (size_t)(b0 + rb + 2) * NHID + hcol);
          uint32_t* q3 = (uint32_t*)(out + (size_t)STATES_ELEMS + (size_t)(b0 + rb + 3) * NHID + hcol);
          store4_plain(q0, q1, q2, q3, fbits(s0), fbits(s1), fbits(s2), fbits(s3));
        }
      }
    }
  };

#pragma unroll 1
  for (int t = 1; t < T_STEPS; t += 2) {
    body(t, 0, uA0, uA1, uA2, uA3, uB0, uB1, uB2, uB3);
    if (t + 1 < T_STEPS)
      body(t + 1, 1, uB0, uB1, uB2, uB3, uA0, uA1, uA2, uA3);
  }
}

// ---------------------------------------------------------------------------
extern "C" void kernel_launch(void* const* d_in, const int* in_sizes, int n_in,
                              void* d_out, int out_size, void* d_ws, size_t ws_size,
                              hipStream_t stream) {
  const float* x  = (const float*)d_in[0];
  const float* Wi = (const float*)d_in[1];
  const float* bi = (const float*)d_in[2];
  const float* Wh = (const float*)d_in[3];
  const float* bh = (const float*)d_in[4];
  float* out = (float*)d_out;
  uint32_t* exch = (uint32_t*)d_ws;  // 512 KB: fast [0,256K) + slow [256K,512K)
  // registry (16 dwords) after the exchange buffers; guarded by ws_size
  uint32_t* reg = (ws_size >= (size_t)(512 * 1024 + 64)) ? (exch + 131072) : nullptr;

  hipLaunchKernelGGL(phase1_gemm, dim3(8, 1024), dim3(256), 0, stream, x, Wi, bi, out, reg);
  hipLaunchKernelGGL(phase2_scan, dim3(128), dim3(256), 0, stream, Wh, bh, out, exch, reg);
}